// Round 4
// baseline (284.757 us; speedup 1.0000x reference)
//
#include <hip/hip_runtime.h>

// ---------------- problem constants ----------------
#define BATCH     16
#define T_LEN     480000
#define PAD       512
#define TPAD      481024      // T_LEN + 2*PAD
#define HOP       256
#define NFRAMES   1876        // (TPAD - NFFT)/HOP + 1
#define FRPAD     1920        // frames padded to 15 blocks of 128 per batch
#define NOUTROW   1026        // 513 freqs * 2 (re,im interleaved)
#define KTOT      1024
#define NCOLS     1152        // padded B columns: 9 tiles of 128 (cols >=1026 are zero)

// ---------------- GEMM tile config ----------------
#define BM        128
#define BN        128
#define BK        32
#define KSTEPS    (KTOT / BK)
#define ACH       4352        // A chunks (16B) staged per block = 69632 B LDS
#define XPSTRIDE  493568      // padded xp row stride: 1792*256 + ACH*8  (256-divisible)

typedef __attribute__((ext_vector_type(8))) short short8;
typedef __attribute__((ext_vector_type(4))) float floatx4;

__device__ __forceinline__ unsigned short f2bf(float f) {
  union { float f; unsigned int u; } v; v.f = f;
  unsigned int u = v.u;
  return (unsigned short)((u + 0x7FFFu + ((u >> 16) & 1u)) >> 16); // RNE
}

// Reflect-padded signal as bf16, row stride XPSTRIDE, tail zero-filled.
// Vectorized x8: fast path is two float4 loads + one short8 store.
__global__ __launch_bounds__(256) void build_xp(const float* __restrict__ x,
                                                unsigned short* __restrict__ xp) {
  const int i0 = (blockIdx.x * 256 + threadIdx.x) * 8;   // [0, XPSTRIDE) step 8
  const int b  = blockIdx.y;
  const float* xb = x + (size_t)b * T_LEN;
  const int j0 = i0 - PAD;
  union { short8 v; unsigned short u[8]; } o;
  if (j0 >= 0 && j0 + 8 <= T_LEN) {                      // interior (vast majority)
    const float4 lo = *(const float4*)(xb + j0);
    const float4 hi = *(const float4*)(xb + j0 + 4);
    o.u[0] = f2bf(lo.x); o.u[1] = f2bf(lo.y); o.u[2] = f2bf(lo.z); o.u[3] = f2bf(lo.w);
    o.u[4] = f2bf(hi.x); o.u[5] = f2bf(hi.y); o.u[6] = f2bf(hi.z); o.u[7] = f2bf(hi.w);
  } else {                                               // reflect edges + zero tail
#pragma unroll
    for (int e = 0; e < 8; ++e) {
      const int i = i0 + e;
      unsigned short v = 0;
      if (i < TPAD) {
        int j = i - PAD;
        if (j < 0) j = -j;
        if (j >= T_LEN) j = 2 * T_LEN - 2 - j;
        v = f2bf(xb[j]);
      }
      o.u[e] = v;
    }
  }
  *(short8*)(xp + (size_t)b * XPSTRIDE + i0) = o.v;
}

// Basis matrix bmat[jcol][k], jcol in [0,1152):
//   jcol = 2f   -> cos(2*pi/1024 * f * k) * w[k]
//   jcol = 2f+1 -> -sin(2*pi/1024 * f * k) * w[k]
// Vectorized x8 along k.
__global__ __launch_bounds__(256) void build_bmat(const float* __restrict__ win,
                                                  unsigned short* __restrict__ bm) {
  const int id = blockIdx.x * 256 + threadIdx.x;   // [0, 1152*128)
  const int j  = id >> 7;                          // 128 threads per row
  const int k0 = (id & 127) * 8;
  union { short8 v; unsigned short u[8]; } o;
  if (j < NOUTROW) {
    const int f = j >> 1;
    const float4 w0 = *(const float4*)(win + k0);
    const float4 w1 = *(const float4*)(win + k0 + 4);
    const float wv[8] = {w0.x, w0.y, w0.z, w0.w, w1.x, w1.y, w1.z, w1.w};
#pragma unroll
    for (int e = 0; e < 8; ++e) {
      const int r = (f * (k0 + e)) & (KTOT - 1);   // exact arg reduction
      const float ang = (float)r * 6.1359231515e-3f;  // 2*pi/1024
      const float c = __cosf(ang), s = __sinf(ang);
      o.u[e] = f2bf(((j & 1) ? -s : c) * wv[e]);
    }
  } else {
#pragma unroll
    for (int e = 0; e < 8; ++e) o.u[e] = 0;
  }
  *(short8*)(bm + (size_t)j * KTOT + k0) = o.v;
}

// C[m][j] = sum_k xp[b][t*HOP + k] * bmat[j][k]
// A staged ONCE in LDS (STFT frame overlap: 68 KB covers all K for 128
// frames). B is NOT staged: bmat (2.36 MB) is L2-resident; each wave loads
// its B fragments global->reg with a 2-deep branch-free pipeline. The
// K-loop has ZERO barriers -- waves self-schedule, L2 latency hides under
// the MFMAs of co-resident waves.
__global__ __launch_bounds__(256, 2) void stft_gemm(const unsigned short* __restrict__ xp,
                                                    const unsigned short* __restrict__ bmat,
                                                    float* __restrict__ out) {
  __shared__ unsigned short As[ACH * 8];   // 69632 B: swizzled signal window

  const int tid  = threadIdx.x;
  const int lane = tid & 63;
  const int wv   = tid >> 6;
  const int wr   = wv >> 1, wc = wv & 1;   // 2x2 waves over 128x128
  const int bx   = blockIdx.x;             // [0,240)
  const int b    = bx / 15;
  const int t0   = (bx - b * 15) * BM;     // frame base, <=1792
  const int j0   = blockIdx.y * BN;        // [0,1152) step 128
  const int L    = lane & 15;
  const int quad = lane >> 4;

  const unsigned short* abase = xp + (size_t)b * XPSTRIDE + (size_t)t0 * HOP;

  // ---- stage A once: LDS chunk ci <- global chunk perm(ci) (involution) ----
#pragma unroll
  for (int r = 0; r < ACH / 256; ++r) {
    const int ci = r * 256 + tid;
    const int s  = ci ^ ((ci >> 5) & 7);
    __builtin_amdgcn_global_load_lds(
        (const __attribute__((address_space(1))) void*)(abase + s * 8),
        (__attribute__((address_space(3))) void*)((char*)As + ci * 16),
        16, 0, 0);
  }

  // B fragment source pointers (global, L2-resident): wave-private columns.
  const unsigned short* bsrcw[4];
#pragma unroll
  for (int t = 0; t < 4; ++t) {
    const int n = wc * 64 + t * 16 + L;
    bsrcw[t] = bmat + (size_t)(j0 + n) * KTOT + quad * 8;
  }

  // A fragment chunk bases: chunk = 32*ml + quad (+ 4*k)
  int sbase[4];
#pragma unroll
  for (int t = 0; t < 4; ++t) {
    const int ml = wr * 64 + t * 16 + L;
    sbase[t] = 32 * ml + quad;
  }

  // ---- prologue: issue B(0), B(1) loads BEFORE the barrier (pure reg) ----
  short8 bcur[4], bnxt[4];
#pragma unroll
  for (int t = 0; t < 4; ++t) bcur[t] = *(const short8*)(bsrcw[t]);
#pragma unroll
  for (int t = 0; t < 4; ++t) bnxt[t] = *(const short8*)(bsrcw[t] + BK);

  __syncthreads();   // drains A global_load_lds; the ONLY block-wide barrier

  short8 acur[4], anxt[4];
#pragma unroll
  for (int t = 0; t < 4; ++t) {
    const int s = sbase[t];
    const int p = s ^ ((s >> 5) & 7);
    acur[t] = *(const short8*)&As[p * 8];
  }

  floatx4 acc[4][4] = {};

  // ---- steady state: k = 0 .. KSTEPS-3, branch-free prefetch of B(k+2), A(k+1)
#pragma unroll 2
  for (int k = 0; k < KSTEPS - 2; ++k) {
    short8 bpre[4];
#pragma unroll
    for (int t = 0; t < 4; ++t)
      bpre[t] = *(const short8*)(bsrcw[t] + (size_t)(k + 2) * BK);
    const int kc = (k + 1) << 2;
#pragma unroll
    for (int t = 0; t < 4; ++t) {
      const int s = sbase[t] + kc;
      const int p = s ^ ((s >> 5) & 7);
      anxt[t] = *(const short8*)&As[p * 8];
    }

    __builtin_amdgcn_s_setprio(1);
#pragma unroll
    for (int ti = 0; ti < 4; ++ti)
#pragma unroll
      for (int tj = 0; tj < 4; ++tj)
        acc[ti][tj] = __builtin_amdgcn_mfma_f32_16x16x32_bf16(
            acur[ti], bcur[tj], acc[ti][tj], 0, 0, 0);
    __builtin_amdgcn_s_setprio(0);

#pragma unroll
    for (int t = 0; t < 4; ++t) {
      acur[t] = anxt[t];
      bcur[t] = bnxt[t];
      bnxt[t] = bpre[t];
    }
  }

  // ---- peel k = KSTEPS-2: prefetch A(KSTEPS-1) only ----
  {
    const int kc = (KSTEPS - 1) << 2;
#pragma unroll
    for (int t = 0; t < 4; ++t) {
      const int s = sbase[t] + kc;
      const int p = s ^ ((s >> 5) & 7);
      anxt[t] = *(const short8*)&As[p * 8];
    }
    __builtin_amdgcn_s_setprio(1);
#pragma unroll
    for (int ti = 0; ti < 4; ++ti)
#pragma unroll
      for (int tj = 0; tj < 4; ++tj)
        acc[ti][tj] = __builtin_amdgcn_mfma_f32_16x16x32_bf16(
            acur[ti], bcur[tj], acc[ti][tj], 0, 0, 0);
    __builtin_amdgcn_s_setprio(0);
#pragma unroll
    for (int t = 0; t < 4; ++t) {
      acur[t] = anxt[t];
      bcur[t] = bnxt[t];
    }
  }

  // ---- peel k = KSTEPS-1: no prefetch ----
  __builtin_amdgcn_s_setprio(1);
#pragma unroll
  for (int ti = 0; ti < 4; ++ti)
#pragma unroll
    for (int tj = 0; tj < 4; ++tj)
      acc[ti][tj] = __builtin_amdgcn_mfma_f32_16x16x32_bf16(
          acur[ti], bcur[tj], acc[ti][tj], 0, 0, 0);
  __builtin_amdgcn_s_setprio(0);

  // ---- epilogue: D[row = quad*4 + i][col = L] per 16x16 tile ----
#pragma unroll
  for (int ti = 0; ti < 4; ++ti) {
    const int tb = t0 + wr * 64 + ti * 16 + quad * 4;
#pragma unroll
    for (int tj = 0; tj < 4; ++tj) {
      const int gj = j0 + wc * 64 + tj * 16 + L;
      if (gj < NOUTROW) {
#pragma unroll
        for (int i = 0; i < 4; ++i) {
          const int t = tb + i;
          if (t < NFRAMES)
            out[(size_t)(b * NFRAMES + t) * NOUTROW + gj] = acc[ti][tj][i];
        }
      }
    }
  }
}

extern "C" void kernel_launch(void* const* d_in, const int* in_sizes, int n_in,
                              void* d_out, int out_size, void* d_ws, size_t ws_size,
                              hipStream_t stream) {
  const float* x   = (const float*)d_in[0];   // (16, 480000) fp32
  const float* win = (const float*)d_in[1];   // (1024,) fp32
  float* out = (float*)d_out;                 // (16, 1876, 513, 2) fp32

  unsigned short* xp   = (unsigned short*)d_ws;                  // 16*493568 bf16 = 15.8 MB
  unsigned short* bmat = xp + (size_t)BATCH * XPSTRIDE;          // 1152*1024 bf16 = 2.36 MB

  build_xp  <<<dim3(XPSTRIDE / 2048, BATCH), 256, 0, stream>>>(x, xp);
  build_bmat<<<dim3(NCOLS * (KTOT / 8) / 256), 256, 0, stream>>>(win, bmat);
  stft_gemm <<<dim3(BATCH * (FRPAD / BM), NCOLS / BN), 256, 0, stream>>>(xp, bmat, out);
}

// Round 6
// 241.161 us; speedup vs baseline: 1.1808x; 1.1808x over previous
//
#include <hip/hip_runtime.h>

// ---------------- problem constants ----------------
#define BATCH     16
#define T_LEN     480000
#define PAD       512
#define TPAD      481024      // T_LEN + 2*PAD
#define HOP       256
#define NFRAMES   1876        // (TPAD - NFFT)/HOP + 1
#define NOUTROW   1026        // 513 freqs * 2 (re,im interleaved)
#define KTOT      1024
#define NCOLS     1152        // padded B columns: 9 tiles of 128 (cols >=1026 are zero)

// ---------------- GEMM tile config ----------------
#define BM        256         // frames per block (A window staged once: 132.6 KB)
#define BN        128
#define BK        32
#define KSTEPS    (KTOT / BK) // 32
#define MTILES    8           // 8*256 = 2048 >= 1876 (tail tiles store-guarded)
#define ACHUNKS   8288        // 16B chunks of A window: 255*256+1024 = 66304 samples
#define ABYTES    (ACHUNKS * 16)        // 132608
#define BBUF      8192        // one B buffer: 128 cols x 32 k x 2B
#define NBUF      3
#define LDSBYTES  (ABYTES + NBUF * BBUF)  // 157184 <= 160 KiB
// XPSTRIDE kept at the harness-PROVEN value (18.15 MB total workspace).
// The last M-tile (t0=1792) reads its A-window up to 63 KB past the row end:
// those bytes land in the NEXT batch's xp row (or, for b=15, in bmat) --
// all inside the allocated workspace, and they only feed frames >= 1925
// (> 1875 = last real frame), which are never stored. No fault, no effect.
#define XPSTRIDE  493568      // 1792*256 + 4352*8, multiple of 2048

typedef __attribute__((ext_vector_type(8))) short short8;
typedef __attribute__((ext_vector_type(4))) float floatx4;

__device__ __forceinline__ unsigned short f2bf(float f) {
  union { float f; unsigned int u; } v; v.f = f;
  unsigned int u = v.u;
  return (unsigned short)((u + 0x7FFFu + ((u >> 16) & 1u)) >> 16); // RNE
}

// Reflect-padded signal as bf16, row stride XPSTRIDE, tail zero-filled.
__global__ __launch_bounds__(256) void build_xp(const float* __restrict__ x,
                                                unsigned short* __restrict__ xp) {
  const int i0 = (blockIdx.x * 256 + threadIdx.x) * 8;   // [0, XPSTRIDE) step 8
  const int b  = blockIdx.y;
  const float* xb = x + (size_t)b * T_LEN;
  const int j0 = i0 - PAD;
  union { short8 v; unsigned short u[8]; } o;
  if (j0 >= 0 && j0 + 8 <= T_LEN) {                      // interior (vast majority)
    const float4 lo = *(const float4*)(xb + j0);
    const float4 hi = *(const float4*)(xb + j0 + 4);
    o.u[0] = f2bf(lo.x); o.u[1] = f2bf(lo.y); o.u[2] = f2bf(lo.z); o.u[3] = f2bf(lo.w);
    o.u[4] = f2bf(hi.x); o.u[5] = f2bf(hi.y); o.u[6] = f2bf(hi.z); o.u[7] = f2bf(hi.w);
  } else {                                               // reflect edges + zero tail
#pragma unroll
    for (int e = 0; e < 8; ++e) {
      const int i = i0 + e;
      unsigned short v = 0;
      if (i < TPAD) {
        int j = i - PAD;
        if (j < 0) j = -j;
        if (j >= T_LEN) j = 2 * T_LEN - 2 - j;
        v = f2bf(xb[j]);
      }
      o.u[e] = v;
    }
  }
  *(short8*)(xp + (size_t)b * XPSTRIDE + i0) = o.v;
}

// Basis matrix bmat[jcol][k], jcol in [0,1152): 2f -> cos*w, 2f+1 -> -sin*w.
__global__ __launch_bounds__(256) void build_bmat(const float* __restrict__ win,
                                                  unsigned short* __restrict__ bm) {
  const int id = blockIdx.x * 256 + threadIdx.x;   // [0, 1152*128)
  const int j  = id >> 7;                          // 128 threads per row
  const int k0 = (id & 127) * 8;
  union { short8 v; unsigned short u[8]; } o;
  if (j < NOUTROW) {
    const int f = j >> 1;
    const float4 w0 = *(const float4*)(win + k0);
    const float4 w1 = *(const float4*)(win + k0 + 4);
    const float wv[8] = {w0.x, w0.y, w0.z, w0.w, w1.x, w1.y, w1.z, w1.w};
#pragma unroll
    for (int e = 0; e < 8; ++e) {
      const int r = (f * (k0 + e)) & (KTOT - 1);   // exact arg reduction
      const float ang = (float)r * 6.1359231515e-3f;  // 2*pi/1024
      const float c = __cosf(ang), s = __sinf(ang);
      o.u[e] = f2bf(((j & 1) ? -s : c) * wv[e]);
    }
  } else {
#pragma unroll
    for (int e = 0; e < 8; ++e) o.u[e] = 0;
  }
  *(short8*)(bm + (size_t)j * KTOT + k0) = o.v;
}

// C[m][j] = sum_k xp[b][t*HOP + k] * bmat[j][k]
// 512 thr / 8 waves, wave tile 64x64 (4M x 2N wave grid over 256x128).
// A staged ONCE (132.6 KB, STFT frame overlap). B streamed through a
// 3-buffer LDS rotation via global_load_lds: ONE s_barrier + counted
// vmcnt(1) per K-step (loads stay in flight across barriers; never drained
// to 0 in the loop). B LDS layout [kq][col][8] -> lane-contiguous 16B frag
// reads, bank-conflict-free.
__global__ __launch_bounds__(512, 2) void stft_gemm(const unsigned short* __restrict__ xp,
                                                    const unsigned short* __restrict__ bmat,
                                                    float* __restrict__ out) {
  extern __shared__ unsigned short smem[];
  unsigned short* As = smem;                        // ABYTES
  unsigned short* Bs = smem + ABYTES / 2;           // NBUF x BBUF

  const int tid  = threadIdx.x;            // 0..511
  const int lane = tid & 63;
  const int wv   = tid >> 6;               // 0..7
  const int wr   = wv >> 1;                // 0..3 : M 64-slice
  const int wc   = wv & 1;                 // 0..1 : N 64-slice
  const int L    = lane & 15;
  const int quad = lane >> 4;
  const int b    = blockIdx.x >> 3;
  const int t0   = (blockIdx.x & 7) * BM;  // frame base, <=1792
  const int j0   = blockIdx.y * BN;

  const unsigned short* abase = xp + (size_t)b * XPSTRIDE + (size_t)t0 * HOP;

  // ---- stage A once: LDS chunk ci <- global chunk perm(ci) (involution
  //      within 8-chunk groups, so perm indices stay < ACHUNKS) ----
#pragma unroll
  for (int r = 0; r < 17; ++r) {
    const int ci = r * 512 + tid;
    if (ci < ACHUNKS) {
      const int s = ci ^ ((ci >> 5) & 7);
      __builtin_amdgcn_global_load_lds(
          (const __attribute__((address_space(1))) void*)(abase + s * 8),
          (__attribute__((address_space(3))) void*)((char*)As + ci * 16),
          16, 0, 0);
    }
  }

  // ---- B staging: thread t owns (kq = t>>7, col = t&127); LDS dest is
  //      thread-linear (tid*16) as global_load_lds requires; that linear
  //      order IS the [kq][col][8] transposed layout. ----
  const int scol = tid & 127, skq = tid >> 7;
  const unsigned short* bsrc = bmat + (size_t)(j0 + scol) * KTOT + skq * 8;
  char* bdst = (char*)Bs + tid * 16;       // + p*BBUF per buffer

  // stage B(0)->buf0, B(1)->buf1
  __builtin_amdgcn_global_load_lds(
      (const __attribute__((address_space(1))) void*)(bsrc),
      (__attribute__((address_space(3))) void*)(bdst), 16, 0, 0);
  __builtin_amdgcn_global_load_lds(
      (const __attribute__((address_space(1))) void*)(bsrc + BK),
      (__attribute__((address_space(3))) void*)(bdst + BBUF), 16, 0, 0);

  // Fragment bases. A: chunk = 32*ml + quad (+4 per K-step).
  // B frag [kq=quad][col=n][8]: short offset (quad*128 + n)*8, +4096/buf.
  int sbase[4];
  const unsigned short* bfp[4];
#pragma unroll
  for (int t = 0; t < 4; ++t) {
    const int ml = wr * 64 + t * 16 + L;
    sbase[t] = 32 * ml + quad;
    const int n = wc * 64 + t * 16 + L;
    bfp[t] = Bs + ((size_t)quad * 128 + n) * 8;
  }

  floatx4 acc[4][4] = {};

  // One K-step: fence -> counted vmcnt -> barrier -> issue stage(K+2) ->
  // frag reads (compiler lgkm-counts) -> MFMA.
  // vmcnt ledger (per wave): after wait(1), outstanding = {B(k+1)}; issue
  // B(k+2) -> 2 in flight. Buffer written at step k is read at step k+2;
  // its landing is covered by step k+2's wait(1) + barrier (all waves).
#define GEMM_STEP(KK, CUR, STG, VM)                                            \
  do {                                                                         \
    __builtin_amdgcn_sched_barrier(0);                                         \
    asm volatile("s_waitcnt vmcnt(" #VM ")" ::: "memory");                     \
    __builtin_amdgcn_s_barrier();                                              \
    __builtin_amdgcn_global_load_lds(                                          \
        (const __attribute__((address_space(1))) void*)(bsrc + ((KK) + 2) * BK), \
        (__attribute__((address_space(3))) void*)(bdst + (STG) * BBUF),        \
        16, 0, 0);                                                             \
    const int kc_ = (KK) << 2;                                                 \
    short8 af_[4], bf_[4];                                                     \
    _Pragma("unroll") for (int t = 0; t < 4; ++t) {                            \
      const int s_ = sbase[t] + kc_;                                           \
      const int p_ = s_ ^ ((s_ >> 5) & 7);                                     \
      af_[t] = *(const short8*)&As[p_ * 8];                                    \
      bf_[t] = *(const short8*)(bfp[t] + (CUR) * (BBUF / 2));                  \
    }                                                                          \
    __builtin_amdgcn_s_setprio(1);                                             \
    _Pragma("unroll") for (int ti_ = 0; ti_ < 4; ++ti_)                        \
        _Pragma("unroll") for (int tj_ = 0; tj_ < 4; ++tj_)                    \
            acc[ti_][tj_] = __builtin_amdgcn_mfma_f32_16x16x32_bf16(           \
                af_[ti_], bf_[tj_], acc[ti_][tj_], 0, 0, 0);                   \
    __builtin_amdgcn_s_setprio(0);                                             \
  } while (0)

#define GEMM_TAIL(KK, CUR, VM)                                                 \
  do {                                                                         \
    __builtin_amdgcn_sched_barrier(0);                                         \
    asm volatile("s_waitcnt vmcnt(" #VM ")" ::: "memory");                     \
    __builtin_amdgcn_s_barrier();                                              \
    const int kc_ = (KK) << 2;                                                 \
    short8 af_[4], bf_[4];                                                     \
    _Pragma("unroll") for (int t = 0; t < 4; ++t) {                            \
      const int s_ = sbase[t] + kc_;                                           \
      const int p_ = s_ ^ ((s_ >> 5) & 7);                                     \
      af_[t] = *(const short8*)&As[p_ * 8];                                    \
      bf_[t] = *(const short8*)(bfp[t] + (CUR) * (BBUF / 2));                  \
    }                                                                          \
    __builtin_amdgcn_s_setprio(1);                                             \
    _Pragma("unroll") for (int ti_ = 0; ti_ < 4; ++ti_)                        \
        _Pragma("unroll") for (int tj_ = 0; tj_ < 4; ++tj_)                    \
            acc[ti_][tj_] = __builtin_amdgcn_mfma_f32_16x16x32_bf16(           \
                af_[ti_], bf_[tj_], acc[ti_][tj_], 0, 0, 0);                   \
    __builtin_amdgcn_s_setprio(0);                                             \
  } while (0)

  // steady state: k = 0..29 (stage B(k+2)); buffers rotate mod 3.
  for (int kk = 0; kk < 10; ++kk) {
    const int k = kk * 3;
    GEMM_STEP(k,     0, 2, 1);
    GEMM_STEP(k + 1, 1, 0, 1);
    GEMM_STEP(k + 2, 2, 1, 1);
  }
  // k=30 (buf0; B(31) still in flight), k=31 (buf1; drain)
  GEMM_TAIL(30, 0, 1);
  GEMM_TAIL(31, 1, 0);

  // ---- epilogue: D[row = quad*4 + i][col = L] per 16x16 tile ----
#pragma unroll
  for (int ti = 0; ti < 4; ++ti) {
    const int tb = t0 + wr * 64 + ti * 16 + quad * 4;
#pragma unroll
    for (int tj = 0; tj < 4; ++tj) {
      const int gj = j0 + wc * 64 + tj * 16 + L;
      if (gj < NOUTROW) {
#pragma unroll
        for (int i = 0; i < 4; ++i) {
          const int t = tb + i;
          if (t < NFRAMES)
            out[(size_t)(b * NFRAMES + t) * NOUTROW + gj] = acc[ti][tj][i];
        }
      }
    }
  }
}

extern "C" void kernel_launch(void* const* d_in, const int* in_sizes, int n_in,
                              void* d_out, int out_size, void* d_ws, size_t ws_size,
                              hipStream_t stream) {
  const float* x   = (const float*)d_in[0];   // (16, 480000) fp32
  const float* win = (const float*)d_in[1];   // (1024,) fp32
  float* out = (float*)d_out;                 // (16, 1876, 513, 2) fp32

  unsigned short* xp   = (unsigned short*)d_ws;                  // 16*493568 bf16 = 15.79 MB
  unsigned short* bmat = xp + (size_t)BATCH * XPSTRIDE;          // 1152*1024 bf16 = 2.36 MB

  (void)hipFuncSetAttribute((const void*)stft_gemm,
                            hipFuncAttributeMaxDynamicSharedMemorySize,
                            LDSBYTES);

  build_xp  <<<dim3(XPSTRIDE / 2048, BATCH), 256, 0, stream>>>(x, xp);
  build_bmat<<<dim3(NCOLS * (KTOT / 8) / 256), 256, 0, stream>>>(win, bmat);
  stft_gemm <<<dim3(BATCH * MTILES, NCOLS / BN), 512, LDSBYTES, stream>>>(xp, bmat, out);
}